// Round 2
// baseline (822.836 us; speedup 1.0000x reference)
//
#include <hip/hip_runtime.h>
#include <hip/hip_bf16.h>

#define D 1024
#define KW 4
#define SEQL 8192
#define BATCH 4
#define MROWS (BATCH*SEQL)   // 32768
#define SEG 128
#define NSEG (SEQL/SEG)      // 64

using bf16 = __hip_bfloat16;
typedef __attribute__((ext_vector_type(8))) short bf16x8_t;   // 8 bf16 = 4 VGPR
typedef __attribute__((ext_vector_type(4))) float f32x4_t;
typedef __attribute__((ext_vector_type(4))) int i32x4_t;

__device__ __forceinline__ float sigmoid_f(float x){ return 1.0f/(1.0f + __expf(-x)); }

// ---------------- weight prep: fp32 -> bf16, concat [Wr;Wi] ----------------
__global__ __launch_bounds__(256) void prep_k(const float* __restrict__ Wr, const float* __restrict__ Wi,
                                              const float* __restrict__ Wrb, const float* __restrict__ Wib,
                                              const float* __restrict__ Wo,
                                              bf16* __restrict__ W1, bf16* __restrict__ Wob,
                                              float* __restrict__ b1){
  int idx = blockIdx.x*256 + threadIdx.x;
  if (idx < 2*D*D){
    int n = idx >> 10;
    float v = (n < D) ? Wr[idx] : Wi[idx - D*D];
    W1[idx] = __float2bfloat16(v);
  } else if (idx < 3*D*D){
    int j = idx - 2*D*D;
    Wob[j] = __float2bfloat16(Wo[j]);
  }
  if (idx < 2*D){
    b1[idx] = (idx < D) ? Wrb[idx] : Wib[idx - D];
  }
}

// ---------------- causal depthwise conv ----------------
__global__ __launch_bounds__(256) void conv_k(const float* __restrict__ x, const float* __restrict__ w,
                                              const float* __restrict__ bias,
                                              float* __restrict__ xc, bf16* __restrict__ xcb){
  size_t idx = (size_t)blockIdx.x*256 + threadIdx.x;   // == m*D + c
  int c = (int)(idx & (D-1));
  int m = (int)(idx >> 10);
  int l = m & (SEQL-1);
  float w0=w[c*KW+0], w1=w[c*KW+1], w2=w[c*KW+2], w3=w[c*KW+3];
  const float* xm = x + idx;
  float v3 = xm[0];
  float v2 = (l>=1)? xm[-(int)D]   : 0.f;
  float v1 = (l>=2)? xm[-(int)(2*D)] : 0.f;
  float v0 = (l>=3)? xm[-(int)(3*D)] : 0.f;
  float acc = bias[c] + w0*v0 + w1*v1 + w2*v2 + w3*v3;
  xc[idx]  = acc;
  xcb[idx] = __float2bfloat16(acc);
}

// ---------------- bf16 GEMM: C[m,n] = sum_k A[m,k]*B[n,k] (+ bias[n]) ----------------
template<typename OutT> __device__ __forceinline__ void store_cvt(OutT* p, float v);
template<> __device__ __forceinline__ void store_cvt<float>(float* p, float v){ *p = v; }
template<> __device__ __forceinline__ void store_cvt<bf16>(bf16* p, float v){ *p = __float2bfloat16(v); }

template<typename OutT, bool HB>
__global__ __launch_bounds__(256) void gemm_bt(const bf16* __restrict__ A, const bf16* __restrict__ B,
                                               const float* __restrict__ bias, OutT* __restrict__ C,
                                               int M, int N, int K){
  __shared__ bf16 As[128][40];   // pitch 40 elems (80B): 2-way bank aliasing = free
  __shared__ bf16 Bs[128][40];
  const int t    = threadIdx.x;
  const int m0   = blockIdx.x * 128;
  const int n0   = blockIdx.y * 128;
  const int wave = t >> 6, lane = t & 63;
  const int wm   = (wave >> 1) * 64, wn = (wave & 1) * 64;
  const int lrow = lane & 15, quad = lane >> 4;

  f32x4_t acc[4][4];
  #pragma unroll
  for (int i=0;i<4;i++)
    #pragma unroll
    for (int j=0;j<4;j++) acc[i][j] = (f32x4_t){0.f,0.f,0.f,0.f};

  const int rowA = t >> 2;          // 0..63
  const int cc8  = (t & 3) * 8;     // k-chunk within tile
  const bf16* Ap = A + (size_t)(m0 + rowA)*K + cc8;
  const bf16* Bp = B + (size_t)(n0 + rowA)*K + cc8;
  const size_t rstep = (size_t)64*K;

  for (int k0 = 0; k0 < K; k0 += 32){
    i32x4_t av0 = *(const i32x4_t*)(Ap + k0);
    i32x4_t av1 = *(const i32x4_t*)(Ap + k0 + rstep);
    i32x4_t bv0 = *(const i32x4_t*)(Bp + k0);
    i32x4_t bv1 = *(const i32x4_t*)(Bp + k0 + rstep);
    __syncthreads();
    *(i32x4_t*)&As[rowA   ][cc8] = av0;
    *(i32x4_t*)&As[rowA+64][cc8] = av1;
    *(i32x4_t*)&Bs[rowA   ][cc8] = bv0;
    *(i32x4_t*)&Bs[rowA+64][cc8] = bv1;
    __syncthreads();
    bf16x8_t af[4], bfr[4];
    #pragma unroll
    for (int i=0;i<4;i++) af[i]  = *(const bf16x8_t*)&As[wm + i*16 + lrow][quad*8];
    #pragma unroll
    for (int i=0;i<4;i++) bfr[i] = *(const bf16x8_t*)&Bs[wn + i*16 + lrow][quad*8];
    #pragma unroll
    for (int i=0;i<4;i++)
      #pragma unroll
      for (int j=0;j<4;j++)
        acc[i][j] = __builtin_amdgcn_mfma_f32_16x16x32_bf16(af[i], bfr[j], acc[i][j], 0, 0, 0);
  }

  #pragma unroll
  for (int i=0;i<4;i++){
    #pragma unroll
    for (int j=0;j<4;j++){
      int gm0 = m0 + wm + i*16 + quad*4;        // C row = quad*4 + reg
      int gn  = n0 + wn + j*16 + lrow;          // C col = lane&15
      float bv = HB ? bias[gn] : 0.f;
      #pragma unroll
      for (int r=0;r<4;r++){
        float v = acc[i][j][r] + bv;
        store_cvt(&C[(size_t)(gm0 + r)*N + gn], v);
      }
    }
  }
}

// ---------------- scan pass 1: segment-local (Aprod, Hend) ----------------
// ri holds raw logits [zr | zi]; sigmoid applied here.
__global__ __launch_bounds__(256) void scan1_k(const bf16* __restrict__ ri, const float* __restrict__ xc,
                                               const float* __restrict__ log_a,
                                               float* __restrict__ Aprod, float* __restrict__ Hend){
  int idx = blockIdx.x*256 + threadIdx.x;       // (b, s, c)
  int c  = idx & (D-1);
  int bs = idx >> 10;
  int s  = bs & (NSEG-1);
  int b  = bs >> 6;
  size_t m0 = (size_t)b*SEQL + (size_t)s*SEG;
  float la = log_a[c];
  float c1 = -8.f * log1pf(__expf(-la));        // 8*log(sigmoid(la)), accurate near 0
  float A = 1.f, h = 0.f;
  for (int l=0; l<SEG; l++){
    size_t m = m0 + l;
    float zr = __bfloat162float(ri[m*(2*D) + c]);
    float zi = __bfloat162float(ri[m*(2*D) + D + c]);
    float xv = xc[m*D + c];
    float r  = sigmoid_f(zr);
    float iv = sigmoid_f(zi);
    float a  = __expf(c1 * r);
    float bt = sqrtf(fmaxf(1.f - a*a, 1e-6f)) * iv * xv;
    A *= a;
    h = fmaf(a, h, bt);
  }
  Aprod[idx] = A;
  Hend[idx]  = h;
}

// ---------------- scan pass 2: cross-segment carry ----------------
__global__ __launch_bounds__(256) void scan2_k(const float* __restrict__ Aprod, const float* __restrict__ Hend,
                                               float* __restrict__ carry){
  int idx = blockIdx.x*256 + threadIdx.x;       // (b, c): 4096 total
  int c = idx & (D-1);
  int b = idx >> 10;
  float h = 0.f;
  #pragma unroll 8
  for (int s=0; s<NSEG; s++){
    int j = ((b*NSEG + s) << 10) + c;
    carry[j] = h;
    h = fmaf(Aprod[j], h, Hend[j]);
  }
}

// ---------------- scan pass 3: recompute + apply carry, emit h (bf16) ----------------
__global__ __launch_bounds__(256) void scan3_k(const bf16* __restrict__ ri, const float* __restrict__ xc,
                                               const float* __restrict__ log_a, const float* __restrict__ carry,
                                               bf16* __restrict__ hbuf){
  int idx = blockIdx.x*256 + threadIdx.x;
  int c  = idx & (D-1);
  int bs = idx >> 10;
  int s  = bs & (NSEG-1);
  int b  = bs >> 6;
  size_t m0 = (size_t)b*SEQL + (size_t)s*SEG;
  float la = log_a[c];
  float c1 = -8.f * log1pf(__expf(-la));
  float h = carry[idx];
  for (int l=0; l<SEG; l++){
    size_t m = m0 + l;
    float zr = __bfloat162float(ri[m*(2*D) + c]);
    float zi = __bfloat162float(ri[m*(2*D) + D + c]);
    float xv = xc[m*D + c];
    float r  = sigmoid_f(zr);
    float iv = sigmoid_f(zi);
    float a  = __expf(c1 * r);
    float bt = sqrtf(fmaxf(1.f - a*a, 1e-6f)) * iv * xv;
    h = fmaf(a, h, bt);
    hbuf[m*D + c] = __float2bfloat16(h);
  }
}

// ---------------- RMSNorm (in-place on d_out) ----------------
__global__ __launch_bounds__(256) void rms_k(float* __restrict__ y, const float* __restrict__ nw){
  int row = blockIdx.x;
  int t   = threadIdx.x;
  float* yr = y + (size_t)row*D;
  f32x4_t v = *(const f32x4_t*)(yr + t*4);
  float ss = v[0]*v[0] + v[1]*v[1] + v[2]*v[2] + v[3]*v[3];
  #pragma unroll
  for (int off=32; off>0; off>>=1) ss += __shfl_down(ss, off);
  __shared__ float red[4];
  if ((t & 63) == 0) red[t>>6] = ss;
  __syncthreads();
  float tot = red[0] + red[1] + red[2] + red[3];
  float scale = rsqrtf(tot * (1.f/D) + 1e-6f);
  f32x4_t w = *(const f32x4_t*)(nw + t*4);
  f32x4_t o;
  #pragma unroll
  for (int k=0;k<4;k++) o[k] = v[k]*scale*w[k];
  *(f32x4_t*)(yr + t*4) = o;
}

extern "C" void kernel_launch(void* const* d_in, const int* in_sizes, int n_in,
                              void* d_out, int out_size, void* d_ws, size_t ws_size,
                              hipStream_t stream) {
  const float* x     = (const float*)d_in[0];
  const float* convw = (const float*)d_in[1];
  const float* convb = (const float*)d_in[2];
  const float* Wr_w  = (const float*)d_in[3];
  const float* Wr_b  = (const float*)d_in[4];
  const float* Wi_w  = (const float*)d_in[5];
  const float* Wi_b  = (const float*)d_in[6];
  const float* log_a = (const float*)d_in[7];
  const float* out_w = (const float*)d_in[8];
  const float* norm_w= (const float*)d_in[9];

  char* ws = (char*)d_ws;
  size_t off = 0;
  auto alloc = [&](size_t bytes)->char*{ char* p = ws + off; off += (bytes + 255) & ~(size_t)255; return p; };

  float* xc    = (float*)alloc((size_t)MROWS*D*4);       // 128 MB, fp32 x_conv
  bf16*  xcb   = (bf16*) alloc((size_t)MROWS*D*2);       // 64 MB, bf16 x_conv (GEMM A)
  bf16*  ri    = (bf16*) alloc((size_t)MROWS*2*D*2);     // 128 MB, raw logits [zr|zi]
  bf16*  hbuf  = (bf16*) alloc((size_t)MROWS*D*2);       // 64 MB, scan result (GEMM2 A)
  bf16*  W1    = (bf16*) alloc((size_t)2*D*D*2);         // 4 MB
  bf16*  Wob   = (bf16*) alloc((size_t)D*D*2);           // 2 MB
  float* b1    = (float*)alloc((size_t)2*D*4);
  float* Aprod = (float*)alloc((size_t)BATCH*NSEG*D*4);  // 1 MB
  float* Hend  = (float*)alloc((size_t)BATCH*NSEG*D*4);
  float* carry = (float*)alloc((size_t)BATCH*NSEG*D*4);
  float* y     = (float*)d_out;                          // GEMM2 output, rmsnorm in-place

  // 1. weight prep
  prep_k<<<dim3((3*D*D + 255)/256), dim3(256), 0, stream>>>(Wr_w, Wi_w, Wr_b, Wi_b, out_w, W1, Wob, b1);
  // 2. conv
  conv_k<<<dim3((size_t)MROWS*D/256), dim3(256), 0, stream>>>(x, convw, convb, xc, xcb);
  // 3. GEMM1: raw logits + bias -> ri (bf16), N=2048  (sigmoid applied in scan)
  gemm_bt<bf16, true><<<dim3(MROWS/128, (2*D)/128), dim3(256), 0, stream>>>(xcb, W1, b1, ri, MROWS, 2*D, D);
  // 4-6. blocked scan
  scan1_k<<<dim3(BATCH*NSEG*D/256), dim3(256), 0, stream>>>(ri, xc, log_a, Aprod, Hend);
  scan2_k<<<dim3(BATCH*D/256), dim3(256), 0, stream>>>(Aprod, Hend, carry);
  scan3_k<<<dim3(BATCH*NSEG*D/256), dim3(256), 0, stream>>>(ri, xc, log_a, carry, hbuf);
  // 7. GEMM2: y = h @ out_w^T (fp32 out, no bias)
  gemm_bt<float, false><<<dim3(MROWS/128, D/128), dim3(256), 0, stream>>>(hbuf, Wob, nullptr, y, MROWS, D, D);
  // 8. RMSNorm in-place on d_out
  rms_k<<<dim3(MROWS), dim3(256), 0, stream>>>(y, norm_w);
}

// Round 4
// 801.824 us; speedup vs baseline: 1.0262x; 1.0262x over previous
//
#include <hip/hip_runtime.h>
#include <hip/hip_bf16.h>

#define D 1024
#define KW 4
#define SEQL 8192
#define BATCH 4
#define MROWS (BATCH*SEQL)   // 32768
#define SEG 128
#define NSEG (SEQL/SEG)      // 64

using bf16 = __hip_bfloat16;
typedef __attribute__((ext_vector_type(8))) short bf16x8_t;   // 8 bf16 = 4 VGPR
typedef __attribute__((ext_vector_type(4))) float f32x4_t;

__device__ __forceinline__ float sigmoid_f(float x){ return 1.0f/(1.0f + __expf(-x)); }

__device__ __forceinline__ void gload_lds16(const bf16* g, bf16* l){
  __builtin_amdgcn_global_load_lds(
    (const __attribute__((address_space(1))) unsigned int*)g,
    (__attribute__((address_space(3))) unsigned int*)l,
    16, 0, 0);
}

__device__ __forceinline__ void bf16x2_unpack(unsigned int u, float& lo, float& hi){
  union { unsigned int i; float f; } a, b;
  a.i = (u & 0xffffu) << 16;
  b.i = u & 0xffff0000u;
  lo = a.f; hi = b.f;
}
__device__ __forceinline__ unsigned int bf16x2_pack(float lo, float hi){
  unsigned short l = __builtin_bit_cast(unsigned short, __float2bfloat16(lo));
  unsigned short h = __builtin_bit_cast(unsigned short, __float2bfloat16(hi));
  return (unsigned int)l | ((unsigned int)h << 16);
}

// ---------------- weight prep: fp32 -> bf16, concat [Wr;Wi] ----------------
__global__ __launch_bounds__(256) void prep_k(const float* __restrict__ Wr, const float* __restrict__ Wi,
                                              const float* __restrict__ Wrb, const float* __restrict__ Wib,
                                              const float* __restrict__ Wo,
                                              bf16* __restrict__ W1, bf16* __restrict__ Wob,
                                              float* __restrict__ b1){
  int idx = blockIdx.x*256 + threadIdx.x;
  if (idx < 2*D*D){
    int n = idx >> 10;
    float v = (n < D) ? Wr[idx] : Wi[idx - D*D];
    W1[idx] = __float2bfloat16(v);
  } else if (idx < 3*D*D){
    int j = idx - 2*D*D;
    Wob[j] = __float2bfloat16(Wo[j]);
  }
  if (idx < 2*D){
    b1[idx] = (idx < D) ? Wrb[idx] : Wib[idx - D];
  }
}

// ---------------- causal depthwise conv (2 channels/thread, bf16 out only) ----------------
__global__ __launch_bounds__(256) void conv_k(const float* __restrict__ x, const float* __restrict__ w,
                                              const float* __restrict__ bias,
                                              unsigned int* __restrict__ xcb){   // bf16x2
  int idx = blockIdx.x*256 + threadIdx.x;   // (m, c2), c2 in [0,512)
  int c2 = idx & 511;
  int c  = c2 * 2;
  int m  = idx >> 9;
  int l  = m & (SEQL-1);
  const float* wp = w + c*KW;               // 8 consecutive floats (2 channels x 4 taps)
  float2 b2 = *(const float2*)(bias + c);
  const float* xm = x + (size_t)m*D + c;
  float2 v3 = *(const float2*)xm;
  float2 v2 = (l>=1)? *(const float2*)(xm - D)   : make_float2(0.f,0.f);
  float2 v1 = (l>=2)? *(const float2*)(xm - 2*D) : make_float2(0.f,0.f);
  float2 v0 = (l>=3)? *(const float2*)(xm - 3*D) : make_float2(0.f,0.f);
  float a0 = b2.x + wp[0]*v0.x + wp[1]*v1.x + wp[2]*v2.x + wp[3]*v3.x;
  float a1 = b2.y + wp[4]*v0.y + wp[5]*v1.y + wp[6]*v2.y + wp[7]*v3.y;
  xcb[idx] = bf16x2_pack(a0, a1);
}

// ---------------- bf16 GEMM (m97 structure): C[m,n] = sum_k A[m,k]*B[n,k] (+ bias[n]) ----------------
template<typename OutT> __device__ __forceinline__ void store_cvt(OutT* p, float v);
template<> __device__ __forceinline__ void store_cvt<float>(float* p, float v){ *p = v; }
template<> __device__ __forceinline__ void store_cvt<bf16>(bf16* p, float v){ *p = __float2bfloat16(v); }

template<typename OutT, bool HB>
__global__ __launch_bounds__(256) void gemm_bt(const bf16* __restrict__ A, const bf16* __restrict__ B,
                                               const float* __restrict__ bias, OutT* __restrict__ C,
                                               int M, int N, int K){
  __shared__ bf16 As[128][32];   // pitch 32: REQUIRED by global_load_lds lane-order deposit (no pad)
  __shared__ bf16 Bs[128][32];
  const int t    = threadIdx.x;
  const int m0   = blockIdx.x * 128;
  const int n0   = blockIdx.y * 128;
  const int wave = t >> 6, lane = t & 63;
  const int wm   = (wave >> 1) * 64, wn = (wave & 1) * 64;
  const int lrow = lane & 15, quad = lane >> 4;

  f32x4_t acc[4][4];
  #pragma unroll
  for (int i=0;i<4;i++)
    #pragma unroll
    for (int j=0;j<4;j++) acc[i][j] = (f32x4_t){0.f,0.f,0.f,0.f};

  // staging: wave handles 32 A-rows + 32 B-rows, 2 DMA instrs each (16 rows x 64B = 1KB/instr)
  const int srow = lane >> 2;        // 0..15
  const int sk8  = (lane & 3) * 8;   // element offset within 32-wide k-chunk
  const bf16* Ag = A + (size_t)(m0 + wave*32 + srow)*K + sk8;
  const bf16* Bg = B + (size_t)(n0 + wave*32 + srow)*K + sk8;
  bf16* As0 = &As[wave*32     ][0];
  bf16* As1 = &As[wave*32 + 16][0];
  bf16* Bs0 = &Bs[wave*32     ][0];
  bf16* Bs1 = &Bs[wave*32 + 16][0];
  const size_t r16 = (size_t)16*K;

  for (int k0 = 0; k0 < K; k0 += 32){
    __syncthreads();                       // LDS reuse guard (prev iter's ds_reads done)
    gload_lds16(Ag + k0,       As0);
    gload_lds16(Ag + k0 + r16, As1);
    gload_lds16(Bg + k0,       Bs0);
    gload_lds16(Bg + k0 + r16, Bs1);
    __syncthreads();                       // vmcnt(0) drain + barrier -> tiles visible
    bf16x8_t af[4], bfr[4];
    #pragma unroll
    for (int i=0;i<4;i++) af[i]  = *(const bf16x8_t*)&As[wm + i*16 + lrow][quad*8];
    #pragma unroll
    for (int i=0;i<4;i++) bfr[i] = *(const bf16x8_t*)&Bs[wn + i*16 + lrow][quad*8];
    #pragma unroll
    for (int i=0;i<4;i++)
      #pragma unroll
      for (int j=0;j<4;j++)
        acc[i][j] = __builtin_amdgcn_mfma_f32_16x16x32_bf16(af[i], bfr[j], acc[i][j], 0, 0, 0);
  }

  #pragma unroll
  for (int i=0;i<4;i++){
    #pragma unroll
    for (int j=0;j<4;j++){
      int gm0 = m0 + wm + i*16 + quad*4;        // C row = quad*4 + reg
      int gn  = n0 + wn + j*16 + lrow;          // C col = lane&15
      float bv = HB ? bias[gn] : 0.f;
      #pragma unroll
      for (int r=0;r<4;r++){
        float v = acc[i][j][r] + bv;
        store_cvt(&C[(size_t)(gm0 + r)*N + gn], v);
      }
    }
  }
}

// ---------------- scan pass 1: segment-local (Aprod, Hend), 2 channels/thread ----------------
__global__ __launch_bounds__(256) void scan1_k(const unsigned int* __restrict__ ri,    // bf16x2 [zr|zi]
                                               const unsigned int* __restrict__ xcb,   // bf16x2
                                               const float* __restrict__ log_a,
                                               float* __restrict__ Aprod, float* __restrict__ Hend){
  int idx = blockIdx.x*256 + threadIdx.x;       // (b, s, c2)
  int c2 = idx & 511;
  int c  = c2*2;
  int bs = idx >> 9;
  int s  = bs & (NSEG-1);
  int b  = bs >> 6;
  size_t m0 = (size_t)b*SEQL + (size_t)s*SEG;
  float2 la = *(const float2*)(log_a + c);
  float c1x = -8.f * log1pf(__expf(-la.x));     // 8*log(sigmoid(la))
  float c1y = -8.f * log1pf(__expf(-la.y));
  float Ax=1.f, Ay=1.f, hx=0.f, hy=0.f;
  for (int l=0; l<SEG; l++){
    size_t m = m0 + l;
    float zrx, zry, zix, ziy, xvx, xvy;
    bf16x2_unpack(ri[m*D + c2],        zrx, zry);   // ri row = 2048 bf16 = 1024 uints; zr at c2
    bf16x2_unpack(ri[m*D + 512 + c2],  zix, ziy);   // zi at 512+c2
    bf16x2_unpack(xcb[m*512 + c2],     xvx, xvy);
    float ax = __expf(c1x * sigmoid_f(zrx));
    float ay = __expf(c1y * sigmoid_f(zry));
    float btx = sqrtf(fmaxf(1.f - ax*ax, 1e-6f)) * sigmoid_f(zix) * xvx;
    float bty = sqrtf(fmaxf(1.f - ay*ay, 1e-6f)) * sigmoid_f(ziy) * xvy;
    Ax *= ax; Ay *= ay;
    hx = fmaf(ax, hx, btx);
    hy = fmaf(ay, hy, bty);
  }
  *(float2*)(Aprod + 2*idx) = make_float2(Ax, Ay);
  *(float2*)(Hend  + 2*idx) = make_float2(hx, hy);
}

// ---------------- scan pass 2: cross-segment carry ----------------
__global__ __launch_bounds__(256) void scan2_k(const float* __restrict__ Aprod, const float* __restrict__ Hend,
                                               float* __restrict__ carry){
  int idx = blockIdx.x*256 + threadIdx.x;       // (b, c): 4096 total
  int c = idx & (D-1);
  int b = idx >> 10;
  float h = 0.f;
  #pragma unroll 8
  for (int s=0; s<NSEG; s++){
    int j = ((b*NSEG + s) << 10) + c;
    carry[j] = h;
    h = fmaf(Aprod[j], h, Hend[j]);
  }
}

// ---------------- scan pass 3: recompute + carry, emit h (bf16x2) ----------------
__global__ __launch_bounds__(256) void scan3_k(const unsigned int* __restrict__ ri,
                                               const unsigned int* __restrict__ xcb,
                                               const float* __restrict__ log_a, const float* __restrict__ carry,
                                               unsigned int* __restrict__ hbuf){
  int idx = blockIdx.x*256 + threadIdx.x;
  int c2 = idx & 511;
  int c  = c2*2;
  int bs = idx >> 9;
  int s  = bs & (NSEG-1);
  int b  = bs >> 6;
  size_t m0 = (size_t)b*SEQL + (size_t)s*SEG;
  float2 la = *(const float2*)(log_a + c);
  float c1x = -8.f * log1pf(__expf(-la.x));
  float c1y = -8.f * log1pf(__expf(-la.y));
  float2 h2 = *(const float2*)(carry + 2*idx);
  float hx = h2.x, hy = h2.y;
  for (int l=0; l<SEG; l++){
    size_t m = m0 + l;
    float zrx, zry, zix, ziy, xvx, xvy;
    bf16x2_unpack(ri[m*D + c2],       zrx, zry);
    bf16x2_unpack(ri[m*D + 512 + c2], zix, ziy);
    bf16x2_unpack(xcb[m*512 + c2],    xvx, xvy);
    float ax = __expf(c1x * sigmoid_f(zrx));
    float ay = __expf(c1y * sigmoid_f(zry));
    float btx = sqrtf(fmaxf(1.f - ax*ax, 1e-6f)) * sigmoid_f(zix) * xvx;
    float bty = sqrtf(fmaxf(1.f - ay*ay, 1e-6f)) * sigmoid_f(ziy) * xvy;
    hx = fmaf(ax, hx, btx);
    hy = fmaf(ay, hy, bty);
    hbuf[m*512 + c2] = bf16x2_pack(hx, hy);
  }
}

// ---------------- RMSNorm (in-place on d_out) ----------------
__global__ __launch_bounds__(256) void rms_k(float* __restrict__ y, const float* __restrict__ nw){
  int row = blockIdx.x;
  int t   = threadIdx.x;
  float* yr = y + (size_t)row*D;
  f32x4_t v = *(const f32x4_t*)(yr + t*4);
  float ss = v[0]*v[0] + v[1]*v[1] + v[2]*v[2] + v[3]*v[3];
  #pragma unroll
  for (int off=32; off>0; off>>=1) ss += __shfl_down(ss, off);
  __shared__ float red[4];
  if ((t & 63) == 0) red[t>>6] = ss;
  __syncthreads();
  float tot = red[0] + red[1] + red[2] + red[3];
  float scale = rsqrtf(tot * (1.f/D) + 1e-6f);
  f32x4_t w = *(const f32x4_t*)(nw + t*4);
  f32x4_t o;
  #pragma unroll
  for (int k=0;k<4;k++) o[k] = v[k]*scale*w[k];
  *(f32x4_t*)(yr + t*4) = o;
}

extern "C" void kernel_launch(void* const* d_in, const int* in_sizes, int n_in,
                              void* d_out, int out_size, void* d_ws, size_t ws_size,
                              hipStream_t stream) {
  const float* x     = (const float*)d_in[0];
  const float* convw = (const float*)d_in[1];
  const float* convb = (const float*)d_in[2];
  const float* Wr_w  = (const float*)d_in[3];
  const float* Wr_b  = (const float*)d_in[4];
  const float* Wi_w  = (const float*)d_in[5];
  const float* Wi_b  = (const float*)d_in[6];
  const float* log_a = (const float*)d_in[7];
  const float* out_w = (const float*)d_in[8];
  const float* norm_w= (const float*)d_in[9];

  char* ws = (char*)d_ws;
  size_t off = 0;
  auto alloc = [&](size_t bytes)->char*{ char* p = ws + off; off += (bytes + 255) & ~(size_t)255; return p; };

  bf16*  xcb   = (bf16*) alloc((size_t)MROWS*D*2);       // 64 MB, bf16 x_conv
  bf16*  ri    = (bf16*) alloc((size_t)MROWS*2*D*2);     // 128 MB, raw logits [zr|zi]
  bf16*  hbuf  = (bf16*) alloc((size_t)MROWS*D*2);       // 64 MB, scan result (GEMM2 A)
  bf16*  W1    = (bf16*) alloc((size_t)2*D*D*2);         // 4 MB
  bf16*  Wob   = (bf16*) alloc((size_t)D*D*2);           // 2 MB
  float* b1    = (float*)alloc((size_t)2*D*4);
  float* Aprod = (float*)alloc((size_t)BATCH*NSEG*D*4);  // 1 MB
  float* Hend  = (float*)alloc((size_t)BATCH*NSEG*D*4);
  float* carry = (float*)alloc((size_t)BATCH*NSEG*D*4);
  float* y     = (float*)d_out;                          // GEMM2 output, rmsnorm in-place

  // 1. weight prep
  prep_k<<<dim3((3*D*D + 255)/256), dim3(256), 0, stream>>>(Wr_w, Wi_w, Wr_b, Wi_b, out_w, W1, Wob, b1);
  // 2. conv -> bf16 only
  conv_k<<<dim3(MROWS*(D/2)/256), dim3(256), 0, stream>>>(x, convw, convb, (unsigned int*)xcb);
  // 3. GEMM1: raw logits + bias -> ri (bf16), N=2048  (sigmoid applied in scan)
  gemm_bt<bf16, true><<<dim3(MROWS/128, (2*D)/128), dim3(256), 0, stream>>>(xcb, W1, b1, ri, MROWS, 2*D, D);
  // 4-6. blocked scan (2 channels/thread)
  scan1_k<<<dim3(BATCH*NSEG*(D/2)/256), dim3(256), 0, stream>>>((const unsigned int*)ri, (const unsigned int*)xcb, log_a, Aprod, Hend);
  scan2_k<<<dim3(BATCH*D/256), dim3(256), 0, stream>>>(Aprod, Hend, carry);
  scan3_k<<<dim3(BATCH*NSEG*(D/2)/256), dim3(256), 0, stream>>>((const unsigned int*)ri, (const unsigned int*)xcb, log_a, carry, (unsigned int*)hbuf);
  // 7. GEMM2: y = h @ out_w^T (fp32 out, no bias)
  gemm_bt<float, false><<<dim3(MROWS/128, D/128), dim3(256), 0, stream>>>(hbuf, Wob, nullptr, y, MROWS, D, D);
  // 8. RMSNorm in-place on d_out
  rms_k<<<dim3(MROWS), dim3(256), 0, stream>>>(y, norm_w);
}